// Round 7
// baseline (257.081 us; speedup 1.0000x reference)
//
#include <hip/hip_runtime.h>
#include <math.h>

// Problem constants
#define BB 8
#define SS 1024
#define DD 512
#define HH 4
#define HD 128
#define N_SC (BB*HH*SS*SS)              // 2^25 score elements

// Rank-histogram: linear bins over |s| <= 0.625 (7 sigma for 128-dim cosines).
// bin = floor(|s| * NB/0.625); log-rank error <= hazard*width/2 ~ 3e-3.
#define NB 8192
#define BINS 13107.2f                   // NB / 0.625
#define NBLK 2048                       // scores blocks
#define NP2 32                          // stage-2 partial count

// Workspace layout (bytes)
#define OFF_QN    0                                  // bf16 normalized Q [bh][s][128]
#define SZ_QN     ((size_t)BB*SS*DD*2)               // 8388608
#define OFF_KN    (OFF_QN + SZ_QN)
#define OFF_VT    (OFF_KN + SZ_QN)                   // bf16 V^T [bh][d=128][s=1024]
#define OFF_PARTS (OFF_VT + SZ_QN)                   // byte-packed uint32[NBLK][NB/4]
#define SZ_PARTS  ((size_t)NBLK*(NB/4)*4)            // 16777216
#define OFF_WMAG  (OFF_PARTS + SZ_PARTS)             // ushort bf16 wmag[NB]
#define OFF_PART2 (OFF_WMAG + (size_t)NB*2)          // uint[NP2][NB]

typedef __bf16 bf16x8 __attribute__((ext_vector_type(8)));
typedef float  f32x4  __attribute__((ext_vector_type(4)));
typedef unsigned short ushort_t;

__device__ __forceinline__ unsigned bf16rne(float x) {   // RNE fp32->bf16 bits
  unsigned b = __float_as_uint(x);
  return (b + 0x7FFFu + ((b >> 16) & 1u)) >> 16;
}
__device__ __forceinline__ unsigned sbin(float s) {
  return (unsigned)fminf(fabsf(s)*BINS, 8191.0f);
}

// ---------------------------------------------------------------------------
// prep_vt: blocks [0,16384): normalize Q,K rows fp32 -> bf16 [bh][s][128].
//          blocks [16384,17408): V fp32 -> bf16 V^T [bh][d][s] via LDS tile.
__global__ __launch_bounds__(256) void prep_vt_kernel(
    const float* __restrict__ q, const float* __restrict__ k,
    const float* __restrict__ v,
    unsigned* __restrict__ qn, unsigned* __restrict__ kn,
    unsigned* __restrict__ vt) {
  __shared__ float T[64][65];
  int t = threadIdx.x;
  if (blockIdx.x < 16384) {
    int lane = t & 63;
    int row = blockIdx.x*4 + (t >> 6);          // 0..65535
    const float* src; unsigned* dst; int r;
    if (row < 32768) { src = q; dst = qn; r = row; }
    else             { src = k; dst = kn; r = row - 32768; }
    int b = r >> 12, s = (r >> 2) & 1023, h = r & 3;
    float2 vv = *(const float2*)(src + ((size_t)(b*1024 + s))*512 + h*128 + lane*2);
    float sum = vv.x*vv.x + vv.y*vv.y;
    #pragma unroll
    for (int off = 32; off; off >>= 1) sum += __shfl_xor(sum, off, 64);
    float inv = rsqrtf(sum);
    unsigned u = bf16rne(vv.x*inv) | (bf16rne(vv.y*inv) << 16);
    dst[(size_t)((b*4 + h)*1024 + s)*64 + lane] = u;
  } else {
    int vb = blockIdx.x - 16384;                // 0..1023
    int s0 = (vb & 15)*64, d0 = ((vb >> 4) & 1)*64, bh = vb >> 5;
    int b = bh >> 2, h = bh & 3;
    #pragma unroll
    for (int i = 0; i < 16; i++) {
      int idx = t + i*256, rs = idx >> 6, cd = idx & 63;
      T[rs][cd] = v[((size_t)(b*1024 + s0 + rs))*512 + h*128 + d0 + cd];
    }
    __syncthreads();
    #pragma unroll
    for (int i = 0; i < 8; i++) {
      int idx = t + i*256, rd = idx >> 5, c2 = (idx & 31)*2;
      unsigned u = bf16rne(T[c2][rd]) | (bf16rne(T[c2+1][rd]) << 16);
      vt[(size_t)(bh*128 + d0 + rd)*512 + (s0 + c2)/2] = u;
    }
  }
}

// ---------------------------------------------------------------------------
// scores_hist: per 128x128 tile, QK^T bf16 MFMA; bin fp32 accumulators into a
// byte-packed LDS histogram; write non-atomic partials. Linear grid with
// bh = id&31 so id%8 = bh%8: all blocks of one head land on one XCD (L2 reuse).
__global__ __launch_bounds__(256) void scores_hist_kernel(
    const ushort_t* __restrict__ qn, const ushort_t* __restrict__ kn,
    unsigned* __restrict__ parts) {
  __shared__ ushort_t Qs[128*128];     // 32 KB
  __shared__ ushort_t Ks[128*128];     // 32 KB
  __shared__ unsigned h8[NB/4];        // 8 KB byte-packed histogram
  int t = threadIdx.x;
  int L = blockIdx.x;                  // 0..2047
  int bh = L & 31, tile = L >> 5;
  int sq0 = (tile >> 3)*128, sk0 = (tile & 7)*128;

  #pragma unroll
  for (int i = 0; i < 8; i++) h8[t + i*256] = 0;

  const uint4* qg = (const uint4*)qn + (size_t)(bh*1024 + sq0)*16;
  const uint4* kg = (const uint4*)kn + (size_t)(bh*1024 + sk0)*16;
  #pragma unroll
  for (int i = 0; i < 8; i++) {
    int idx = t + i*256, row = idx >> 4, g = idx & 15;
    int sw = g ^ (row & 15);
    *(uint4*)&Qs[row*128 + sw*8] = qg[row*16 + g];
    *(uint4*)&Ks[row*128 + sw*8] = kg[row*16 + g];
  }
  __syncthreads();

  int w = t >> 6, lane = t & 63, m16 = lane & 15, q2 = lane >> 4;
  int wm = (w >> 1)*64, wn = (w & 1)*64;
  f32x4 acc[4][4];
  #pragma unroll
  for (int i = 0; i < 4; i++)
    #pragma unroll
    for (int j = 0; j < 4; j++) acc[i][j] = (f32x4){0.f,0.f,0.f,0.f};

  #pragma unroll
  for (int ks = 0; ks < 4; ks++) {
    int sw = ((ks*4 + q2) ^ m16)*8;
    bf16x8 a[4], bb[4];
    #pragma unroll
    for (int i = 0; i < 4; i++) a[i]  = *(const bf16x8*)&Qs[(wm + i*16 + m16)*128 + sw];
    #pragma unroll
    for (int j = 0; j < 4; j++) bb[j] = *(const bf16x8*)&Ks[(wn + j*16 + m16)*128 + sw];
    #pragma unroll
    for (int i = 0; i < 4; i++)
      #pragma unroll
      for (int j = 0; j < 4; j++)
        acc[i][j] = __builtin_amdgcn_mfma_f32_16x16x32_bf16(a[i], bb[j], acc[i][j], 0, 0, 0);
  }

  // bin all 64 accumulator values (linear |s| bins -> negligible contention)
  #pragma unroll
  for (int i = 0; i < 4; i++)
    #pragma unroll
    for (int j = 0; j < 4; j++)
      #pragma unroll
      for (int p = 0; p < 4; p++) {
        unsigned bin = sbin(acc[i][j][p]);
        atomicAdd(&h8[bin >> 2], 1u << ((bin & 3)*8));
      }
  __syncthreads();

  unsigned* dst = parts + (size_t)L*(NB/4);
  #pragma unroll
  for (int i = 0; i < 8; i++) dst[t + i*256] = h8[t + i*256];
}

// ---------------------------------------------------------------------------
// reduce1: grid (8, NP2) x 256 thr. Block (gx,gy) sums byte-packed partials
// [64*gy, 64*gy+64) for word-column g = gx*256+t; writes unpacked uint counts.
__global__ __launch_bounds__(256) void reduce1_kernel(
    const unsigned* __restrict__ parts, unsigned* __restrict__ parts2) {
  int g = blockIdx.x*256 + threadIdx.x;       // 0..2047 word-column
  int p0 = blockIdx.y*64;
  unsigned s0 = 0, s1 = 0, s2 = 0, s3 = 0;
  #pragma unroll 8
  for (int p = p0; p < p0 + 64; p++) {
    unsigned w = parts[(size_t)p*(NB/4) + g];
    s0 += w & 0xFFu; s1 += (w >> 8) & 0xFFu;
    s2 += (w >> 16) & 0xFFu; s3 += w >> 24;
  }
  uint4 o = {s0, s1, s2, s3};
  ((uint4*)parts2)[(size_t)blockIdx.y*(NB/4) + g] = o;
}

// ---------------------------------------------------------------------------
// scan: single block; fold NP2 uint partials, prefix-scan, emit bf16 wmag.
// wmag[b] = -log((n - P_inc[b] + 0.5*(cnt[b]+1))/n)
__global__ __launch_bounds__(1024) void scan_kernel(
    const unsigned* __restrict__ parts2, ushort_t* __restrict__ wmag) {
  __shared__ unsigned d[1024];
  int t = threadIdx.x;
  unsigned loc[8] = {0,0,0,0,0,0,0,0};
  #pragma unroll 4
  for (int p = 0; p < NP2; p++) {
    uint4 a = ((const uint4*)parts2)[(size_t)p*(NB/4) + t*2];
    uint4 b2 = ((const uint4*)parts2)[(size_t)p*(NB/4) + t*2 + 1];
    loc[0] += a.x;  loc[1] += a.y;  loc[2] += a.z;  loc[3] += a.w;
    loc[4] += b2.x; loc[5] += b2.y; loc[6] += b2.z; loc[7] += b2.w;
  }
  unsigned tot = 0;
  #pragma unroll
  for (int j = 0; j < 8; j++) tot += loc[j];
  d[t] = tot; __syncthreads();
  for (int off = 1; off < 1024; off <<= 1) {
    unsigned x = (t >= off) ? d[t - off] : 0u;
    __syncthreads();
    d[t] += x;
    __syncthreads();
  }
  unsigned run = d[t] - tot;            // exclusive prefix
  const float inv_n = 1.0f / (float)N_SC;
  #pragma unroll
  for (int j = 0; j < 8; j++) {
    run += loc[j];
    float rm = (float)(N_SC - run) + 0.5f*(float)(loc[j] + 1u);
    wmag[t*8 + j] = (ushort_t)bf16rne(-logf(rm * inv_n));
  }
}

// ---------------------------------------------------------------------------
// out: per (b,h), 64 q-rows x 128 d. Pipelined: vt B-frags prefetched into
// registers behind QK^T; next Ks chunk prefetched behind transform+PV;
// 2 barriers/kc. Linear grid, bh = id&31 pins each head to one XCD.
__global__ __launch_bounds__(256) void out_kernel(
    const ushort_t* __restrict__ qn, const ushort_t* __restrict__ kn,
    const ushort_t* __restrict__ wmag, const ushort_t* __restrict__ vt,
    float* __restrict__ out) {
  __shared__ ushort_t Qs[64*128];      // 16 KB
  __shared__ ushort_t Ks[128*128];     // 32 KB
  __shared__ ushort_t Ws[64*128];      // 16 KB
  __shared__ ushort_t Wl[NB];          // 16 KB bf16 wmag table
  int t = threadIdx.x;
  int L = blockIdx.x;                  // 0..511
  int bh = L & 31, q0 = (L >> 5)*64;
  int b = bh >> 2, h = bh & 3;

  #pragma unroll
  for (int i = 0; i < 4; i++)
    ((uint4*)Wl)[t + i*256] = ((const uint4*)wmag)[t + i*256];

  const uint4* qg = (const uint4*)qn + (size_t)(bh*1024 + q0)*16;
  #pragma unroll
  for (int i = 0; i < 4; i++) {
    int idx = t + i*256, row = idx >> 4, g = idx & 15;
    *(uint4*)&Qs[row*128 + (g ^ (row & 15))*8] = qg[row*16 + g];
  }

  // prologue: stage Ks chunk 0
  int srow = t >> 1, sg8 = (t & 1)*8;        // thread -> 2 rows? no: idx decomp below
  (void)srow; (void)sg8;
  uint4 kreg[8];
  {
    const uint4* kg = (const uint4*)kn + (size_t)(bh*1024)*16;
    #pragma unroll
    for (int i = 0; i < 8; i++) {
      int idx = t + i*256, row = idx >> 4, g = idx & 15;
      kreg[i] = kg[row*16 + g];
    }
    #pragma unroll
    for (int i = 0; i < 8; i++) {
      int idx = t + i*256, row = idx >> 4, g = idx & 15;
      *(uint4*)&Ks[row*128 + (g ^ (row & 15))*8] = kreg[i];
    }
  }

  int w = t >> 6, lane = t & 63, m16 = lane & 15, q2 = lane >> 4;
  int wq = (w >> 1)*32, wd = (w & 1)*64;
  f32x4 oacc[2][4];
  #pragma unroll
  for (int i = 0; i < 2; i++)
    #pragma unroll
    for (int j = 0; j < 4; j++) oacc[i][j] = (f32x4){0.f,0.f,0.f,0.f};

  const uint4* vg = (const uint4*)vt;
  for (int kc = 0; kc < 8; kc++) {
    __syncthreads();                   // B1: Ks(kc) visible; PV(kc-1) complete

    // prefetch vt B-frags for this kc (consumed after B2 -> hidden by QK^T)
    uint4 vreg[16];
    #pragma unroll
    for (int ks = 0; ks < 4; ks++)
      #pragma unroll
      for (int j = 0; j < 4; j++)
        vreg[ks*4+j] = vg[(size_t)(bh*128 + wd + j*16 + m16)*128 + kc*16 + ks*4 + q2];

    // QK^T: 32q x 64k' (2x4 tiles), same chain as scores_hist (bin-consistent)
    f32x4 sacc[2][4];
    #pragma unroll
    for (int i = 0; i < 2; i++)
      #pragma unroll
      for (int j = 0; j < 4; j++) sacc[i][j] = (f32x4){0.f,0.f,0.f,0.f};
    #pragma unroll
    for (int ks = 0; ks < 4; ks++) {
      int sw = ((ks*4 + q2) ^ m16)*8;
      bf16x8 a[2], bb[4];
      #pragma unroll
      for (int i = 0; i < 2; i++) a[i]  = *(const bf16x8*)&Qs[(wq + i*16 + m16)*128 + sw];
      #pragma unroll
      for (int j = 0; j < 4; j++) bb[j] = *(const bf16x8*)&Ks[(wd + j*16 + m16)*128 + sw];
      #pragma unroll
      for (int i = 0; i < 2; i++)
        #pragma unroll
        for (int j = 0; j < 4; j++)
          sacc[i][j] = __builtin_amdgcn_mfma_f32_16x16x32_bf16(a[i], bb[j], sacc[i][j], 0, 0, 0);
    }

    // prefetch next Ks chunk into registers (LDS write deferred past PV)
    int kc2 = (kc < 7) ? kc + 1 : 7;
    {
      const uint4* kg = (const uint4*)kn + (size_t)(bh*1024 + kc2*128)*16;
      #pragma unroll
      for (int i = 0; i < 8; i++) {
        int idx = t + i*256, row = idx >> 4, g = idx & 15;
        kreg[i] = kg[row*16 + g];
      }
    }

    // transform own sacc -> Ws (disjoint region per wave-pair; others may
    // still be in QK^T reading Ks -- different buffer, safe)
    #pragma unroll
    for (int i = 0; i < 2; i++)
      #pragma unroll
      for (int j = 0; j < 4; j++)
        #pragma unroll
        for (int p = 0; p < 4; p++) {
          float s = sacc[i][j][p];
          unsigned wm = (s == 0.f) ? 0u
                        : (unsigned)Wl[sbin(s)] | ((s < 0.f) ? 0x8000u : 0u);
          int row = wq + i*16 + q2*4 + p;
          int col = wd + j*16 + m16;
          Ws[row*128 + ((col >> 3) ^ (row & 15))*8 + (col & 7)] = (ushort_t)wm;
        }
    __syncthreads();                   // B2: Ws fully written

    // PV: A from Ws (LDS), B from prefetched vreg
    #pragma unroll
    for (int ks = 0; ks < 4; ks++) {
      int sw = ((ks*4 + q2) ^ m16)*8;
      bf16x8 a[2];
      #pragma unroll
      for (int i = 0; i < 2; i++) a[i] = *(const bf16x8*)&Ws[(wq + i*16 + m16)*128 + sw];
      #pragma unroll
      for (int i = 0; i < 2; i++)
        #pragma unroll
        for (int j = 0; j < 4; j++)
          oacc[i][j] = __builtin_amdgcn_mfma_f32_16x16x32_bf16(
              a[i], *(const bf16x8*)&vreg[ks*4+j], oacc[i][j], 0, 0, 0);
    }

    // write next Ks chunk (all waves past QK^T(kc) via B2; visible at next B1)
    #pragma unroll
    for (int i = 0; i < 8; i++) {
      int idx = t + i*256, row = idx >> 4, g = idx & 15;
      *(uint4*)&Ks[row*128 + (g ^ (row & 15))*8] = kreg[i];
    }
  }

  #pragma unroll
  for (int i = 0; i < 2; i++)
    #pragma unroll
    for (int p = 0; p < 4; p++) {
      int qrow = q0 + wq + i*16 + q2*4 + p;
      #pragma unroll
      for (int j = 0; j < 4; j++) {
        int dcol = wd + j*16 + m16;
        out[(size_t)(b*1024 + qrow)*512 + h*128 + dcol] = oacc[i][j][p];
      }
    }
}

// ---------------------------------------------------------------------------
extern "C" void kernel_launch(void* const* d_in, const int* in_sizes, int n_in,
                              void* d_out, int out_size, void* d_ws, size_t ws_size,
                              hipStream_t stream) {
  const float* q = (const float*)d_in[0];
  const float* k = (const float*)d_in[1];
  const float* v = (const float*)d_in[2];
  float* out = (float*)d_out;
  char* ws = (char*)d_ws;

  unsigned* qn    = (unsigned*)(ws + OFF_QN);
  unsigned* kn    = (unsigned*)(ws + OFF_KN);
  unsigned* vtb   = (unsigned*)(ws + OFF_VT);
  unsigned* parts = (unsigned*)(ws + OFF_PARTS);
  ushort_t* wmag  = (ushort_t*)(ws + OFF_WMAG);
  unsigned* part2 = (unsigned*)(ws + OFF_PART2);

  hipLaunchKernelGGL(prep_vt_kernel, dim3(17408), dim3(256), 0, stream, q, k, v, qn, kn, vtb);
  hipLaunchKernelGGL(scores_hist_kernel, dim3(NBLK), dim3(256), 0, stream,
                     (const ushort_t*)qn, (const ushort_t*)kn, parts);
  hipLaunchKernelGGL(reduce1_kernel, dim3(8, NP2), dim3(256), 0, stream, parts, part2);
  hipLaunchKernelGGL(scan_kernel, dim3(1), dim3(1024), 0, stream, part2, wmag);
  hipLaunchKernelGGL(out_kernel, dim3(512), dim3(256), 0, stream,
                     (const ushort_t*)qn, (const ushort_t*)kn, wmag,
                     (const ushort_t*)vtb, out);
}

// Round 8
// 192.223 us; speedup vs baseline: 1.3374x; 1.3374x over previous
//
#include <hip/hip_runtime.h>
#include <math.h>

// Problem constants
#define BB 8
#define SS 1024
#define DD 512
#define HH 4
#define HD 128
#define N_SC (BB*HH*SS*SS)              // 2^25 score elements

// Rank-histogram: linear bins over |s| <= 0.625 (7 sigma for 128-dim cosines).
// bin = floor(|s| * NB/0.625); log-rank error <= hazard*width/2 ~ 3e-3.
#define NB 8192
#define BINS 13107.2f                   // NB / 0.625
#define NBLK 2048                       // scores blocks
#define NP2 32                          // stage-2 partial count

// Workspace layout (bytes)
#define OFF_QN    0                                  // bf16 normalized Q [bh][s][128]
#define SZ_QN     ((size_t)BB*SS*DD*2)               // 8388608
#define OFF_KN    (OFF_QN + SZ_QN)
#define OFF_VT    (OFF_KN + SZ_QN)                   // bf16 V^T [bh][d=128][s=1024]
#define OFF_PARTS (OFF_VT + SZ_QN)                   // byte-packed uint32[NBLK][NB/4]
#define SZ_PARTS  ((size_t)NBLK*(NB/4)*4)            // 16777216
#define OFF_WMAG  (OFF_PARTS + SZ_PARTS)             // ushort bf16 wmag[NB]
#define OFF_PART2 (OFF_WMAG + (size_t)NB*2)          // uint[NP2][NB]

typedef __bf16 bf16x8 __attribute__((ext_vector_type(8)));
typedef float  f32x4  __attribute__((ext_vector_type(4)));
typedef unsigned short ushort_t;

__device__ __forceinline__ unsigned bf16rne(float x) {   // RNE fp32->bf16 bits
  unsigned b = __float_as_uint(x);
  return (b + 0x7FFFu + ((b >> 16) & 1u)) >> 16;
}
__device__ __forceinline__ unsigned sbin(float s) {
  return (unsigned)fminf(fabsf(s)*BINS, 8191.0f);
}

// ---------------------------------------------------------------------------
// prep_vt: blocks [0,16384): normalize Q,K rows fp32 -> bf16 [bh][s][128].
//          blocks [16384,17408): V fp32 -> bf16 V^T [bh][d][s] via LDS tile.
__global__ __launch_bounds__(256) void prep_vt_kernel(
    const float* __restrict__ q, const float* __restrict__ k,
    const float* __restrict__ v,
    unsigned* __restrict__ qn, unsigned* __restrict__ kn,
    unsigned* __restrict__ vt) {
  __shared__ float T[64][65];
  int t = threadIdx.x;
  if (blockIdx.x < 16384) {
    int lane = t & 63;
    int row = blockIdx.x*4 + (t >> 6);          // 0..65535
    const float* src; unsigned* dst; int r;
    if (row < 32768) { src = q; dst = qn; r = row; }
    else             { src = k; dst = kn; r = row - 32768; }
    int b = r >> 12, s = (r >> 2) & 1023, h = r & 3;
    float2 vv = *(const float2*)(src + ((size_t)(b*1024 + s))*512 + h*128 + lane*2);
    float sum = vv.x*vv.x + vv.y*vv.y;
    #pragma unroll
    for (int off = 32; off; off >>= 1) sum += __shfl_xor(sum, off, 64);
    float inv = rsqrtf(sum);
    unsigned u = bf16rne(vv.x*inv) | (bf16rne(vv.y*inv) << 16);
    dst[(size_t)((b*4 + h)*1024 + s)*64 + lane] = u;
  } else {
    int vb = blockIdx.x - 16384;                // 0..1023
    int s0 = (vb & 15)*64, d0 = ((vb >> 4) & 1)*64, bh = vb >> 5;
    int b = bh >> 2, h = bh & 3;
    #pragma unroll
    for (int i = 0; i < 16; i++) {
      int idx = t + i*256, rs = idx >> 6, cd = idx & 63;
      T[rs][cd] = v[((size_t)(b*1024 + s0 + rs))*512 + h*128 + d0 + cd];
    }
    __syncthreads();
    #pragma unroll
    for (int i = 0; i < 8; i++) {
      int idx = t + i*256, rd = idx >> 5, c2 = (idx & 31)*2;
      unsigned u = bf16rne(T[c2][rd]) | (bf16rne(T[c2+1][rd]) << 16);
      vt[(size_t)(bh*128 + d0 + rd)*512 + (s0 + c2)/2] = u;
    }
  }
}

// ---------------------------------------------------------------------------
// scores_hist: per 128x128 tile, QK^T bf16 MFMA; bin fp32 accumulators into a
// byte-packed LDS histogram; write non-atomic partials. Linear grid with
// bh = id&31 so id%8 = bh%8: all blocks of one head land on one XCD (L2 reuse).
__global__ __launch_bounds__(256) void scores_hist_kernel(
    const ushort_t* __restrict__ qn, const ushort_t* __restrict__ kn,
    unsigned* __restrict__ parts) {
  __shared__ ushort_t Qs[128*128];     // 32 KB
  __shared__ ushort_t Ks[128*128];     // 32 KB
  __shared__ unsigned h8[NB/4];        // 8 KB byte-packed histogram
  int t = threadIdx.x;
  int L = blockIdx.x;                  // 0..2047
  int bh = L & 31, tile = L >> 5;
  int sq0 = (tile >> 3)*128, sk0 = (tile & 7)*128;

  #pragma unroll
  for (int i = 0; i < 8; i++) h8[t + i*256] = 0;

  const uint4* qg = (const uint4*)qn + (size_t)(bh*1024 + sq0)*16;
  const uint4* kg = (const uint4*)kn + (size_t)(bh*1024 + sk0)*16;
  #pragma unroll
  for (int i = 0; i < 8; i++) {
    int idx = t + i*256, row = idx >> 4, g = idx & 15;
    int sw = g ^ (row & 15);
    *(uint4*)&Qs[row*128 + sw*8] = qg[row*16 + g];
    *(uint4*)&Ks[row*128 + sw*8] = kg[row*16 + g];
  }
  __syncthreads();

  int w = t >> 6, lane = t & 63, m16 = lane & 15, q2 = lane >> 4;
  int wm = (w >> 1)*64, wn = (w & 1)*64;
  f32x4 acc[4][4];
  #pragma unroll
  for (int i = 0; i < 4; i++)
    #pragma unroll
    for (int j = 0; j < 4; j++) acc[i][j] = (f32x4){0.f,0.f,0.f,0.f};

  #pragma unroll
  for (int ks = 0; ks < 4; ks++) {
    int sw = ((ks*4 + q2) ^ m16)*8;
    bf16x8 a[4], bb[4];
    #pragma unroll
    for (int i = 0; i < 4; i++) a[i]  = *(const bf16x8*)&Qs[(wm + i*16 + m16)*128 + sw];
    #pragma unroll
    for (int j = 0; j < 4; j++) bb[j] = *(const bf16x8*)&Ks[(wn + j*16 + m16)*128 + sw];
    #pragma unroll
    for (int i = 0; i < 4; i++)
      #pragma unroll
      for (int j = 0; j < 4; j++)
        acc[i][j] = __builtin_amdgcn_mfma_f32_16x16x32_bf16(a[i], bb[j], acc[i][j], 0, 0, 0);
  }

  // bin all 64 accumulator values (linear |s| bins -> negligible contention)
  #pragma unroll
  for (int i = 0; i < 4; i++)
    #pragma unroll
    for (int j = 0; j < 4; j++)
      #pragma unroll
      for (int p = 0; p < 4; p++) {
        unsigned bin = sbin(acc[i][j][p]);
        atomicAdd(&h8[bin >> 2], 1u << ((bin & 3)*8));
      }
  __syncthreads();

  unsigned* dst = parts + (size_t)L*(NB/4);
  #pragma unroll
  for (int i = 0; i < 8; i++) dst[t + i*256] = h8[t + i*256];
}

// ---------------------------------------------------------------------------
// reduce1: grid (8, NP2) x 256 thr. Block (gx,gy) sums byte-packed partials
// [64*gy, 64*gy+64) for word-column g = gx*256+t; writes unpacked uint counts.
__global__ __launch_bounds__(256) void reduce1_kernel(
    const unsigned* __restrict__ parts, unsigned* __restrict__ parts2) {
  int g = blockIdx.x*256 + threadIdx.x;       // 0..2047 word-column
  int p0 = blockIdx.y*64;
  unsigned s0 = 0, s1 = 0, s2 = 0, s3 = 0;
  #pragma unroll 8
  for (int p = p0; p < p0 + 64; p++) {
    unsigned w = parts[(size_t)p*(NB/4) + g];
    s0 += w & 0xFFu; s1 += (w >> 8) & 0xFFu;
    s2 += (w >> 16) & 0xFFu; s3 += w >> 24;
  }
  uint4 o = {s0, s1, s2, s3};
  ((uint4*)parts2)[(size_t)blockIdx.y*(NB/4) + g] = o;
}

// ---------------------------------------------------------------------------
// scan: single block; fold NP2 uint partials, prefix-scan, emit bf16 wmag.
// wmag[b] = -log((n - P_inc[b] + 0.5*(cnt[b]+1))/n)
__global__ __launch_bounds__(1024) void scan_kernel(
    const unsigned* __restrict__ parts2, ushort_t* __restrict__ wmag) {
  __shared__ unsigned d[1024];
  int t = threadIdx.x;
  unsigned loc[8] = {0,0,0,0,0,0,0,0};
  #pragma unroll 4
  for (int p = 0; p < NP2; p++) {
    uint4 a = ((const uint4*)parts2)[(size_t)p*(NB/4) + t*2];
    uint4 b2 = ((const uint4*)parts2)[(size_t)p*(NB/4) + t*2 + 1];
    loc[0] += a.x;  loc[1] += a.y;  loc[2] += a.z;  loc[3] += a.w;
    loc[4] += b2.x; loc[5] += b2.y; loc[6] += b2.z; loc[7] += b2.w;
  }
  unsigned tot = 0;
  #pragma unroll
  for (int j = 0; j < 8; j++) tot += loc[j];
  d[t] = tot; __syncthreads();
  for (int off = 1; off < 1024; off <<= 1) {
    unsigned x = (t >= off) ? d[t - off] : 0u;
    __syncthreads();
    d[t] += x;
    __syncthreads();
  }
  unsigned run = d[t] - tot;            // exclusive prefix
  const float inv_n = 1.0f / (float)N_SC;
  #pragma unroll
  for (int j = 0; j < 8; j++) {
    run += loc[j];
    float rm = (float)(N_SC - run) + 0.5f*(float)(loc[j] + 1u);
    wmag[t*8 + j] = (ushort_t)bf16rne(-logf(rm * inv_n));
  }
}

// ---------------------------------------------------------------------------
// out: per (b,h), 64 q-rows x 128 d. R6 three-barrier structure (no register
// pipelining -- __syncthreads drains vmcnt(0), so prefetch-across-barrier
// stalls; measured R7). Linear grid, bh = id&31 pins each head to one XCD so
// Ks staging and PV's vt loads hit on-XCD L2.
__global__ __launch_bounds__(256) void out_kernel(
    const ushort_t* __restrict__ qn, const ushort_t* __restrict__ kn,
    const ushort_t* __restrict__ wmag, const ushort_t* __restrict__ vt,
    float* __restrict__ out) {
  __shared__ ushort_t Qs[64*128];      // 16 KB
  __shared__ ushort_t Ks[128*128];     // 32 KB
  __shared__ ushort_t Ws[64*128];      // 16 KB
  __shared__ ushort_t Wl[NB];          // 16 KB bf16 wmag table
  int t = threadIdx.x;
  int L = blockIdx.x;                  // 0..511
  int bh = L & 31, q0 = (L >> 5)*64;
  int b = bh >> 2, h = bh & 3;

  #pragma unroll
  for (int i = 0; i < 4; i++)
    ((uint4*)Wl)[t + i*256] = ((const uint4*)wmag)[t + i*256];

  const uint4* qg = (const uint4*)qn + (size_t)(bh*1024 + q0)*16;
  #pragma unroll
  for (int i = 0; i < 4; i++) {
    int idx = t + i*256, row = idx >> 4, g = idx & 15;
    *(uint4*)&Qs[row*128 + (g ^ (row & 15))*8] = qg[row*16 + g];
  }

  int w = t >> 6, lane = t & 63, m16 = lane & 15, q2 = lane >> 4;
  int wq = (w >> 1)*32, wd = (w & 1)*64;
  f32x4 oacc[2][4];
  #pragma unroll
  for (int i = 0; i < 2; i++)
    #pragma unroll
    for (int j = 0; j < 4; j++) oacc[i][j] = (f32x4){0.f,0.f,0.f,0.f};

  for (int kc = 0; kc < 8; kc++) {
    // stage K chunk rows kc*128..+128 (PV reads Ws/vt only: safe to overwrite)
    const uint4* kg = (const uint4*)kn + (size_t)(bh*1024 + kc*128)*16;
    #pragma unroll
    for (int i = 0; i < 8; i++) {
      int idx = t + i*256, row = idx >> 4, g = idx & 15;
      *(uint4*)&Ks[row*128 + (g ^ (row & 15))*8] = kg[row*16 + g];
    }
    __syncthreads();                   // B1: Ks (and Qs/Wl on kc=0) ready

    // QK^T: wave computes 32q x 64k' (2x4 tiles) -- same accumulation chain
    // as scores_hist (bin-consistent).
    f32x4 sacc[2][4];
    #pragma unroll
    for (int i = 0; i < 2; i++)
      #pragma unroll
      for (int j = 0; j < 4; j++) sacc[i][j] = (f32x4){0.f,0.f,0.f,0.f};
    #pragma unroll
    for (int ks = 0; ks < 4; ks++) {
      int sw = ((ks*4 + q2) ^ m16)*8;
      bf16x8 a[2], bb[4];
      #pragma unroll
      for (int i = 0; i < 2; i++) a[i]  = *(const bf16x8*)&Qs[(wq + i*16 + m16)*128 + sw];
      #pragma unroll
      for (int j = 0; j < 4; j++) bb[j] = *(const bf16x8*)&Ks[(wd + j*16 + m16)*128 + sw];
      #pragma unroll
      for (int i = 0; i < 2; i++)
        #pragma unroll
        for (int j = 0; j < 4; j++)
          sacc[i][j] = __builtin_amdgcn_mfma_f32_16x16x32_bf16(a[i], bb[j], sacc[i][j], 0, 0, 0);
    }
    __syncthreads();                   // B2: all waves done reading Ws (prev PV)

    // transform + C-layout scatter into swizzled Ws (<=2-way bank alias)
    #pragma unroll
    for (int i = 0; i < 2; i++)
      #pragma unroll
      for (int j = 0; j < 4; j++)
        #pragma unroll
        for (int p = 0; p < 4; p++) {
          float s = sacc[i][j][p];
          unsigned wm = (s == 0.f) ? 0u
                        : (unsigned)Wl[sbin(s)] | ((s < 0.f) ? 0x8000u : 0u);
          int row = wq + i*16 + q2*4 + p;
          int col = wd + j*16 + m16;
          Ws[row*128 + ((col >> 3) ^ (row & 15))*8 + (col & 7)] = (ushort_t)wm;
        }
    __syncthreads();                   // B3: Ws ready

    // PV: B-frags straight from global V^T (on-XCD L2 resident, 256KB/head)
    const uint4* vg = (const uint4*)vt;
    #pragma unroll
    for (int ks = 0; ks < 4; ks++) {
      int sw = ((ks*4 + q2) ^ m16)*8;
      bf16x8 a[2], bb[4];
      #pragma unroll
      for (int i = 0; i < 2; i++) a[i] = *(const bf16x8*)&Ws[(wq + i*16 + m16)*128 + sw];
      #pragma unroll
      for (int j = 0; j < 4; j++)
        bb[j] = *(const bf16x8*)&vg[(size_t)(bh*128 + wd + j*16 + m16)*128 + kc*16 + ks*4 + q2];
      #pragma unroll
      for (int i = 0; i < 2; i++)
        #pragma unroll
        for (int j = 0; j < 4; j++)
          oacc[i][j] = __builtin_amdgcn_mfma_f32_16x16x32_bf16(a[i], bb[j], oacc[i][j], 0, 0, 0);
    }
  }

  #pragma unroll
  for (int i = 0; i < 2; i++)
    #pragma unroll
    for (int p = 0; p < 4; p++) {
      int qrow = q0 + wq + i*16 + q2*4 + p;
      #pragma unroll
      for (int j = 0; j < 4; j++) {
        int dcol = wd + j*16 + m16;
        out[(size_t)(b*1024 + qrow)*512 + h*128 + dcol] = oacc[i][j][p];
      }
    }
}

// ---------------------------------------------------------------------------
extern "C" void kernel_launch(void* const* d_in, const int* in_sizes, int n_in,
                              void* d_out, int out_size, void* d_ws, size_t ws_size,
                              hipStream_t stream) {
  const float* q = (const float*)d_in[0];
  const float* k = (const float*)d_in[1];
  const float* v = (const float*)d_in[2];
  float* out = (float*)d_out;
  char* ws = (char*)d_ws;

  unsigned* qn    = (unsigned*)(ws + OFF_QN);
  unsigned* kn    = (unsigned*)(ws + OFF_KN);
  unsigned* vtb   = (unsigned*)(ws + OFF_VT);
  unsigned* parts = (unsigned*)(ws + OFF_PARTS);
  ushort_t* wmag  = (ushort_t*)(ws + OFF_WMAG);
  unsigned* part2 = (unsigned*)(ws + OFF_PART2);

  hipLaunchKernelGGL(prep_vt_kernel, dim3(17408), dim3(256), 0, stream, q, k, v, qn, kn, vtb);
  hipLaunchKernelGGL(scores_hist_kernel, dim3(NBLK), dim3(256), 0, stream,
                     (const ushort_t*)qn, (const ushort_t*)kn, parts);
  hipLaunchKernelGGL(reduce1_kernel, dim3(8, NP2), dim3(256), 0, stream, parts, part2);
  hipLaunchKernelGGL(scan_kernel, dim3(1), dim3(1024), 0, stream, part2, wmag);
  hipLaunchKernelGGL(out_kernel, dim3(512), dim3(256), 0, stream,
                     (const ushort_t*)qn, (const ushort_t*)kn, wmag,
                     (const ushort_t*)vtb, out);
}

// Round 9
// 176.570 us; speedup vs baseline: 1.4560x; 1.0887x over previous
//
#include <hip/hip_runtime.h>
#include <math.h>

// Problem constants
#define BB 8
#define SS 1024
#define DD 512
#define HH 4
#define HD 128
#define N_SC (BB*HH*SS*SS)              // 2^25 score elements

// Rank-histogram: linear bins over |s| <= 0.625 (7 sigma for 128-dim cosines).
// Binned value = the bf16-rounded score (bit-identical to what out reads from S).
#define NB 8192
#define BINS 13107.2f                   // NB / 0.625
#define NBLK 2048                       // scores blocks
#define NP2 32                          // stage-2 partial count

// Workspace layout (bytes)
#define OFF_S     0                                  // bf16 S [bh][q][k]  67 MB
#define SZ_S      ((size_t)N_SC*2)
#define OFF_QN    (OFF_S + SZ_S)                     // bf16 normalized Q [bh][s][128]
#define SZ_QN     ((size_t)BB*SS*DD*2)               // 8388608
#define OFF_KN    (OFF_QN + SZ_QN)
#define OFF_VT    (OFF_KN + SZ_QN)                   // bf16 V^T [bh][d=128][s=1024]
#define OFF_PARTS (OFF_VT + SZ_QN)                   // byte-packed uint32[NBLK][NB/4]
#define SZ_PARTS  ((size_t)NBLK*(NB/4)*4)            // 16777216
#define OFF_WMAG  (OFF_PARTS + SZ_PARTS)             // ushort bf16 wmag[NB]
#define OFF_PART2 (OFF_WMAG + (size_t)NB*2)          // uint[NP2][NB]

typedef __bf16 bf16x8 __attribute__((ext_vector_type(8)));
typedef float  f32x4  __attribute__((ext_vector_type(4)));
typedef unsigned short ushort_t;

__device__ __forceinline__ unsigned bf16rne(float x) {   // RNE fp32->bf16 bits
  unsigned b = __float_as_uint(x);
  return (b + 0x7FFFu + ((b >> 16) & 1u)) >> 16;
}
__device__ __forceinline__ unsigned sbin(float s) {
  return (unsigned)fminf(fabsf(s)*BINS, 8191.0f);
}

// ---------------------------------------------------------------------------
// prep_vt: blocks [0,16384): normalize Q,K rows fp32 -> bf16 [bh][s][128].
//          blocks [16384,17408): V fp32 -> bf16 V^T [bh][d][s] via LDS tile.
__global__ __launch_bounds__(256) void prep_vt_kernel(
    const float* __restrict__ q, const float* __restrict__ k,
    const float* __restrict__ v,
    unsigned* __restrict__ qn, unsigned* __restrict__ kn,
    unsigned* __restrict__ vt) {
  __shared__ float T[64][65];
  int t = threadIdx.x;
  if (blockIdx.x < 16384) {
    int lane = t & 63;
    int row = blockIdx.x*4 + (t >> 6);          // 0..65535
    const float* src; unsigned* dst; int r;
    if (row < 32768) { src = q; dst = qn; r = row; }
    else             { src = k; dst = kn; r = row - 32768; }
    int b = r >> 12, s = (r >> 2) & 1023, h = r & 3;
    float2 vv = *(const float2*)(src + ((size_t)(b*1024 + s))*512 + h*128 + lane*2);
    float sum = vv.x*vv.x + vv.y*vv.y;
    #pragma unroll
    for (int off = 32; off; off >>= 1) sum += __shfl_xor(sum, off, 64);
    float inv = rsqrtf(sum);
    unsigned u = bf16rne(vv.x*inv) | (bf16rne(vv.y*inv) << 16);
    dst[(size_t)((b*4 + h)*1024 + s)*64 + lane] = u;
  } else {
    int vb = blockIdx.x - 16384;                // 0..1023
    int s0 = (vb & 15)*64, d0 = ((vb >> 4) & 1)*64, bh = vb >> 5;
    int b = bh >> 2, h = bh & 3;
    #pragma unroll
    for (int i = 0; i < 16; i++) {
      int idx = t + i*256, rs = idx >> 6, cd = idx & 63;
      T[rs][cd] = v[((size_t)(b*1024 + s0 + rs))*512 + h*128 + d0 + cd];
    }
    __syncthreads();
    #pragma unroll
    for (int i = 0; i < 8; i++) {
      int idx = t + i*256, rd = idx >> 5, c2 = (idx & 31)*2;
      unsigned u = bf16rne(T[c2][rd]) | (bf16rne(T[c2+1][rd]) << 16);
      vt[(size_t)(bh*128 + d0 + rd)*512 + (s0 + c2)/2] = u;
    }
  }
}

// ---------------------------------------------------------------------------
// scores_hist: per 128x128 tile, QK^T bf16 MFMA; store S as bf16; bin the
// bf16-rounded value (bit-consistent with out's S read) into a byte-packed
// LDS histogram; non-atomic partials. bh = id&31 pins heads to XCDs.
__global__ __launch_bounds__(256) void scores_hist_kernel(
    const ushort_t* __restrict__ qn, const ushort_t* __restrict__ kn,
    ushort_t* __restrict__ S, unsigned* __restrict__ parts) {
  __shared__ ushort_t Qs[128*128];     // 32 KB
  __shared__ ushort_t Ks[128*128];     // 32 KB
  __shared__ unsigned h8[NB/4];        // 8 KB byte-packed histogram
  int t = threadIdx.x;
  int L = blockIdx.x;                  // 0..2047
  int bh = L & 31, tile = L >> 5;
  int sq0 = (tile >> 3)*128, sk0 = (tile & 7)*128;

  #pragma unroll
  for (int i = 0; i < 8; i++) h8[t + i*256] = 0;

  const uint4* qg = (const uint4*)qn + (size_t)(bh*1024 + sq0)*16;
  const uint4* kg = (const uint4*)kn + (size_t)(bh*1024 + sk0)*16;
  #pragma unroll
  for (int i = 0; i < 8; i++) {
    int idx = t + i*256, row = idx >> 4, g = idx & 15;
    int sw = g ^ (row & 15);
    *(uint4*)&Qs[row*128 + sw*8] = qg[row*16 + g];
    *(uint4*)&Ks[row*128 + sw*8] = kg[row*16 + g];
  }
  __syncthreads();

  int w = t >> 6, lane = t & 63, m16 = lane & 15, q2 = lane >> 4;
  int wm = (w >> 1)*64, wn = (w & 1)*64;
  f32x4 acc[4][4];
  #pragma unroll
  for (int i = 0; i < 4; i++)
    #pragma unroll
    for (int j = 0; j < 4; j++) acc[i][j] = (f32x4){0.f,0.f,0.f,0.f};

  #pragma unroll
  for (int ks = 0; ks < 4; ks++) {
    int sw = ((ks*4 + q2) ^ m16)*8;
    bf16x8 a[4], bb[4];
    #pragma unroll
    for (int i = 0; i < 4; i++) a[i]  = *(const bf16x8*)&Qs[(wm + i*16 + m16)*128 + sw];
    #pragma unroll
    for (int j = 0; j < 4; j++) bb[j] = *(const bf16x8*)&Ks[(wn + j*16 + m16)*128 + sw];
    #pragma unroll
    for (int i = 0; i < 4; i++)
      #pragma unroll
      for (int j = 0; j < 4; j++)
        acc[i][j] = __builtin_amdgcn_mfma_f32_16x16x32_bf16(a[i], bb[j], acc[i][j], 0, 0, 0);
  }

  // store bf16 S + bin the bf16-rounded value (consistent with out's read)
  size_t Sbase = (size_t)bh << 20;
  #pragma unroll
  for (int i = 0; i < 4; i++)
    #pragma unroll
    for (int p = 0; p < 4; p++) {
      int row = sq0 + wm + i*16 + q2*4 + p;
      #pragma unroll
      for (int j = 0; j < 4; j++) {
        int col = sk0 + wn + j*16 + m16;
        unsigned u = bf16rne(acc[i][j][p]);
        S[Sbase + ((size_t)row << 10) + col] = (ushort_t)u;
        unsigned bin = sbin(__uint_as_float(u << 16));
        atomicAdd(&h8[bin >> 2], 1u << ((bin & 3)*8));
      }
    }
  __syncthreads();

  unsigned* dst = parts + (size_t)L*(NB/4);
  #pragma unroll
  for (int i = 0; i < 8; i++) dst[t + i*256] = h8[t + i*256];
}

// ---------------------------------------------------------------------------
// reduce1: grid (8, NP2) x 256 thr. Block (gx,gy) sums byte-packed partials
// [64*gy, 64*gy+64) for word-column g = gx*256+t; writes unpacked uint counts.
__global__ __launch_bounds__(256) void reduce1_kernel(
    const unsigned* __restrict__ parts, unsigned* __restrict__ parts2) {
  int g = blockIdx.x*256 + threadIdx.x;       // 0..2047 word-column
  int p0 = blockIdx.y*64;
  unsigned s0 = 0, s1 = 0, s2 = 0, s3 = 0;
  #pragma unroll 8
  for (int p = p0; p < p0 + 64; p++) {
    unsigned w = parts[(size_t)p*(NB/4) + g];
    s0 += w & 0xFFu; s1 += (w >> 8) & 0xFFu;
    s2 += (w >> 16) & 0xFFu; s3 += w >> 24;
  }
  uint4 o = {s0, s1, s2, s3};
  ((uint4*)parts2)[(size_t)blockIdx.y*(NB/4) + g] = o;
}

// ---------------------------------------------------------------------------
// scan: single block; fold NP2 uint partials, prefix-scan, emit bf16 wmag.
// wmag[b] = -log((n - P_inc[b] + 0.5*(cnt[b]+1))/n)
__global__ __launch_bounds__(1024) void scan_kernel(
    const unsigned* __restrict__ parts2, ushort_t* __restrict__ wmag) {
  __shared__ unsigned d[1024];
  int t = threadIdx.x;
  unsigned loc[8] = {0,0,0,0,0,0,0,0};
  #pragma unroll 4
  for (int p = 0; p < NP2; p++) {
    uint4 a = ((const uint4*)parts2)[(size_t)p*(NB/4) + t*2];
    uint4 b2 = ((const uint4*)parts2)[(size_t)p*(NB/4) + t*2 + 1];
    loc[0] += a.x;  loc[1] += a.y;  loc[2] += a.z;  loc[3] += a.w;
    loc[4] += b2.x; loc[5] += b2.y; loc[6] += b2.z; loc[7] += b2.w;
  }
  unsigned tot = 0;
  #pragma unroll
  for (int j = 0; j < 8; j++) tot += loc[j];
  d[t] = tot; __syncthreads();
  for (int off = 1; off < 1024; off <<= 1) {
    unsigned x = (t >= off) ? d[t - off] : 0u;
    __syncthreads();
    d[t] += x;
    __syncthreads();
  }
  unsigned run = d[t] - tot;            // exclusive prefix
  const float inv_n = 1.0f / (float)N_SC;
  #pragma unroll
  for (int j = 0; j < 8; j++) {
    run += loc[j];
    float rm = (float)(N_SC - run) + 0.5f*(float)(loc[j] + 1u);
    wmag[t*8 + j] = (ushort_t)bf16rne(-logf(rm * inv_n));
  }
}

// ---------------------------------------------------------------------------
// out: O = W(S) @ V per (b,h). Wave owns 16 q-rows. A-frag (W) is built in
// registers from a contiguous 16B S-row read + Wl transform (A/B frags share
// the [lane&15][quad*8+j] layout, so lane m16's own-row read IS the A-frag).
// No QK^T recompute, no Ws round-trip. Only V^T is LDS-staged per kc
// (2 barriers/kc). LDS 48KB -> 3 blocks/CU. bh = id&31 pins heads to XCDs.
__global__ __launch_bounds__(256) void out_kernel(
    const ushort_t* __restrict__ S, const ushort_t* __restrict__ wmag,
    const ushort_t* __restrict__ vt, float* __restrict__ out) {
  __shared__ ushort_t Vs[128*128];     // 32 KB: V^T chunk [d=128][k=128]
  __shared__ ushort_t Wl[NB];          // 16 KB bf16 wmag table
  int t = threadIdx.x;
  int L = blockIdx.x;                  // 0..511
  int bh = L & 31, q0 = (L >> 5)*64;
  int b = bh >> 2, h = bh & 3;

  #pragma unroll
  for (int i = 0; i < 4; i++)
    ((uint4*)Wl)[t + i*256] = ((const uint4*)wmag)[t + i*256];

  int w = t >> 6, lane = t & 63, m16 = lane & 15, q2 = lane >> 4;
  int qw = q0 + w*16;                  // wave's 16 q-rows; lane's row = qw+m16
  const ushort_t* Srow = S + ((size_t)(bh*1024 + qw + m16) << 10);
  const uint4* vg = (const uint4*)vt + (size_t)bh*128*128;

  f32x4 oacc[8];
  #pragma unroll
  for (int j = 0; j < 8; j++) oacc[j] = (f32x4){0.f,0.f,0.f,0.f};

  for (int kc = 0; kc < 8; kc++) {
    // stage V^T chunk [d 0..128][kc*128 ..+128], coalesced, XOR-swizzled
    #pragma unroll
    for (int i = 0; i < 8; i++) {
      int idx = t + i*256, row = idx >> 4, g = idx & 15;
      *(uint4*)&Vs[row*128 + (g ^ (row & 15))*8] = vg[row*128 + kc*16 + g];
    }
    __syncthreads();                   // B1: Vs ready (Wl too on kc=0)

    #pragma unroll
    for (int ks = 0; ks < 4; ks++) {
      // A-frag: lane reads its q-row's 8 scores (16B contiguous), transforms
      uint4 sv = *(const uint4*)&Srow[kc*128 + ks*32 + q2*8];
      unsigned sc[4] = {sv.x, sv.y, sv.z, sv.w};
      union { bf16x8 v; unsigned u[4]; } af;
      #pragma unroll
      for (int m = 0; m < 4; m++) {
        float flo = __uint_as_float(sc[m] << 16);
        float fhi = __uint_as_float(sc[m] & 0xFFFF0000u);
        unsigned wlo = (flo == 0.f) ? 0u
                       : (unsigned)Wl[sbin(flo)] | ((flo < 0.f) ? 0x8000u : 0u);
        unsigned whi = (fhi == 0.f) ? 0u
                       : (unsigned)Wl[sbin(fhi)] | ((fhi < 0.f) ? 0x8000u : 0u);
        af.u[m] = wlo | (whi << 16);
      }
      // B-frags from Vs; 8 MFMA (d-tiles 0..7)
      int sw = ((ks*4 + q2) ^ m16)*8;
      #pragma unroll
      for (int j = 0; j < 8; j++) {
        bf16x8 bb = *(const bf16x8*)&Vs[(j*16 + m16)*128 + sw];
        oacc[j] = __builtin_amdgcn_mfma_f32_16x16x32_bf16(af.v, bb, oacc[j], 0, 0, 0);
      }
    }
    __syncthreads();                   // B2: all reads done before re-stage
  }

  // epilogue: C-layout store (row=q: q2*4+p, col=d: j*16+m16)
  #pragma unroll
  for (int p = 0; p < 4; p++) {
    int qrow = qw + q2*4 + p;
    #pragma unroll
    for (int j = 0; j < 8; j++)
      out[(size_t)(b*1024 + qrow)*512 + h*128 + j*16 + m16] = oacc[j][p];
  }
}

// ---------------------------------------------------------------------------
extern "C" void kernel_launch(void* const* d_in, const int* in_sizes, int n_in,
                              void* d_out, int out_size, void* d_ws, size_t ws_size,
                              hipStream_t stream) {
  const float* q = (const float*)d_in[0];
  const float* k = (const float*)d_in[1];
  const float* v = (const float*)d_in[2];
  float* out = (float*)d_out;
  char* ws = (char*)d_ws;

  ushort_t* Sbuf  = (ushort_t*)(ws + OFF_S);
  unsigned* qn    = (unsigned*)(ws + OFF_QN);
  unsigned* kn    = (unsigned*)(ws + OFF_KN);
  unsigned* vtb   = (unsigned*)(ws + OFF_VT);
  unsigned* parts = (unsigned*)(ws + OFF_PARTS);
  ushort_t* wmag  = (ushort_t*)(ws + OFF_WMAG);
  unsigned* part2 = (unsigned*)(ws + OFF_PART2);

  hipLaunchKernelGGL(prep_vt_kernel, dim3(17408), dim3(256), 0, stream, q, k, v, qn, kn, vtb);
  hipLaunchKernelGGL(scores_hist_kernel, dim3(NBLK), dim3(256), 0, stream,
                     (const ushort_t*)qn, (const ushort_t*)kn, Sbuf, parts);
  hipLaunchKernelGGL(reduce1_kernel, dim3(8, NP2), dim3(256), 0, stream, parts, part2);
  hipLaunchKernelGGL(scan_kernel, dim3(1), dim3(1024), 0, stream, part2, wmag);
  hipLaunchKernelGGL(out_kernel, dim3(512), dim3(256), 0, stream,
                     (const ushort_t*)Sbuf, wmag, (const ushort_t*)vtb, out);
}